// Round 6
// baseline (277.414 us; speedup 1.0000x reference)
//
#include <hip/hip_runtime.h>
#include <hip/hip_bf16.h>
#include <stdint.h>

// B=16, M=4096, D=64, K=1024. fp32 in / fp32 out.
// Output: [z_q_st (N*D) | indices (N) | loss (1)], fp32.
//
// R18 (resubmit; previous bench died to container infra, no kernel verdict).
// R17 post-mortem: barrier-locked stage->compute structure stuck at ~1
// resident block/CU across R13/R15/R17; ~50% exposed latency at any tile
// size. R18: DELETE the staging pipeline. Codebook bf16 hi/lo = 256KB =
// L2-resident; stream B-fragments straight from L2 into registers. Zero
// barriers, zero LDS in the main loop; explicit 2-deep named double-buffer
// (rule #20) + 4 waves/SIMD of TLP hide ~200cyc L2 latency. L2 floor =
// 4096 waves x 256KB / ~34TB/s ~= 30us; MFMA 12.4us, VALU ~15us fit under.
// Screen math/top-2/fp64-rescan/epilogue byte-identical to R17 (absmax=0):
// bf16 hi/lo hh+hl+lh, MARGIN=0.06 >= 2x err bound; k-map kappa(lg,s,i) =
// lg*16+s*8+i on BOTH A and B frags; C/D row=(l>>4)*4+rg, col=l&15 (m89/m91).
#define D_     64
#define K_     1024
#define N_     65536
#define TPB    256            // 4 waves
#define RPB    64             // 4 waves x 16 rows
#define NBLK   (N_ / RPB)     // 1024 blocks
#define MARGIN 0.06f          // screen err bound ~1.4e-2; need >= 2x

typedef __bf16 bf16x8 __attribute__((ext_vector_type(8)));
typedef float  f32x4  __attribute__((ext_vector_type(4)));

__device__ __forceinline__ unsigned short bf16_rne(float f) {
    union { float f; uint32_t u; } v; v.f = f;
    const uint32_t u = v.u;
    return (unsigned short)((u + 0x7fffu + ((u >> 16) & 1u)) >> 16);
}
__device__ __forceinline__ float bf16_tof(unsigned short h) {
    union { uint32_t u; float f; } v; v.u = ((uint32_t)h) << 16;
    return v.f;
}

// ---------------------------------------------------------------------------
// Kernel A: exact fp64 norms (+fp32 copy) and LINEAR bf16 hi/lo codebook
// (code-major, 128B per code). 4 threads per code; quad shfl-reduce for norm.
// ---------------------------------------------------------------------------
__global__ __launch_bounds__(256) void vq_prep(const float* __restrict__ embed,
                                               double* __restrict__ n64,
                                               float* __restrict__ n32,
                                               unsigned short* __restrict__ ehg,
                                               unsigned short* __restrict__ elg) {
    const int gid = blockIdx.x * 256 + threadIdx.x;   // 4096 threads
    const int k   = gid >> 2;
    const int q4  = gid & 3;                          // quarter of the code
    const float4* e4 = (const float4*)(embed + (size_t)k * D_ + q4 * 16);
    double acc = 0.0;
    uint32_t hw[8], lw[8];
#pragma unroll
    for (int q = 0; q < 4; ++q) {
        const float4 e = e4[q];
        float c[4] = {e.x, e.y, e.z, e.w};
        unsigned short hb[4], lb[4];
#pragma unroll
        for (int j = 0; j < 4; ++j) {
            hb[j] = bf16_rne(c[j]);
            lb[j] = bf16_rne(c[j] - bf16_tof(hb[j]));
            acc = fma((double)c[j], (double)c[j], acc);
        }
        hw[q * 2]     = (uint32_t)hb[0] | ((uint32_t)hb[1] << 16);
        hw[q * 2 + 1] = (uint32_t)hb[2] | ((uint32_t)hb[3] << 16);
        lw[q * 2]     = (uint32_t)lb[0] | ((uint32_t)lb[1] << 16);
        lw[q * 2 + 1] = (uint32_t)lb[2] | ((uint32_t)lb[3] << 16);
    }
    // butterfly over the quad -> all 4 lanes hold the full norm
    acc += __shfl_xor(acc, 1);
    acc += __shfl_xor(acc, 2);
    if (q4 == 0) { n64[k] = acc; n32[k] = (float)acc; }
    char* hp = (char*)ehg + (size_t)k * 128 + q4 * 32;
    char* lp = (char*)elg + (size_t)k * 128 + q4 * 32;
    int4 h0; h0.x = hw[0]; h0.y = hw[1]; h0.z = hw[2]; h0.w = hw[3];
    int4 h1; h1.x = hw[4]; h1.y = hw[5]; h1.z = hw[6]; h1.w = hw[7];
    int4 l0; l0.x = lw[0]; l0.y = lw[1]; l0.z = lw[2]; l0.w = lw[3];
    int4 l1; l1.x = lw[4]; l1.y = lw[5]; l1.z = lw[6]; l1.w = lw[7];
    *(int4*)hp = h0; *(int4*)(hp + 16) = h1;
    *(int4*)lp = l0; *(int4*)(lp + 16) = l1;
}

// ---------------------------------------------------------------------------
// Kernel B: barrier-free MFMA screen streaming B-frags from L2 + fused
// per-row top-2 + exact fp64 rescan + epilogue.
// Wave = 16 rows; lane (lg=l>>4, lc=l&15); A-row = lc, code-in-group = lc.
// ---------------------------------------------------------------------------
__global__ __launch_bounds__(TPB) void vq_main(const float* __restrict__ z_e,
                                               const float* __restrict__ embed,
                                               const unsigned short* __restrict__ ehg,
                                               const unsigned short* __restrict__ elg,
                                               const float* __restrict__ n32g,
                                               const double* __restrict__ n64g,
                                               float* __restrict__ out,
                                               float* __restrict__ partials) {
    __shared__ float red[TPB];          // loss reduction only (1 KB)

    const int tid  = threadIdx.x;
    const int lane = tid & 63;
    const int w    = tid >> 6;          // wave id 0..3
    const int lg   = lane >> 4;         // k-chunk / row-group 0..3
    const int lc   = lane & 15;         // A-row in tile / code in group
    const int wrow0 = blockIdx.x * RPB + w * 16;

    // ---- x row: fp32 slice (dims lg*16..+16) + bf16 hi/lo A-fragments ----
    float  xs[16];
    bf16x8 ah[2], al[2];
    {
        const int row = wrow0 + lc;
        const float4* xg = (const float4*)(z_e + (size_t)row * D_ + lg * 16);
#pragma unroll
        for (int q = 0; q < 4; ++q) {
            const float4 x = xg[q];
            xs[q * 4 + 0] = x.x; xs[q * 4 + 1] = x.y;
            xs[q * 4 + 2] = x.z; xs[q * 4 + 3] = x.w;
        }
#pragma unroll
        for (int s = 0; s < 2; ++s) {
#pragma unroll
            for (int i = 0; i < 8; ++i) {
                const float xf = xs[s * 8 + i];
                const unsigned short hb = bf16_rne(xf);
                const unsigned short lb = bf16_rne(xf - bf16_tof(hb));
                union { unsigned short u; __bf16 h; } uh, ul;
                uh.u = hb; ul.u = lb;
                ah[s][i] = uh.h;
                al[s][i] = ul.h;
            }
        }
    }

    float b1[4], b2[4];
    int   i1[4];
#pragma unroll
    for (int rg = 0; rg < 4; ++rg) { b1[rg] = 3.4e38f; b2[rg] = 3.4e38f; i1[rg] = 0; }

    // ---- barrier-free K loop: 64 groups of 16 codes, 2-deep pipeline ----
    const char* hb = (const char*)ehg;
    const char* lb = (const char*)elg;
    const int   loff = lc * 128 + lg * 32;   // lane's 16B slot in a 2KB group

#define LOADCT(CT, H0, H1, L0, L1, NV) {                                  \
        const int b_ = (CT) * 2048 + loff;                                \
        H0 = *(const int4*)(hb + b_);                                     \
        H1 = *(const int4*)(hb + b_ + 16);                                \
        L0 = *(const int4*)(lb + b_);                                     \
        L1 = *(const int4*)(lb + b_ + 16);                                \
        NV = n32g[(CT) * 16 + lc];                                        \
    }
#define COMPUTECT(CT, H0, H1, L0, L1, NV) {                               \
        const bf16x8 bh0 = __builtin_bit_cast(bf16x8, H0);                \
        const bf16x8 bh1 = __builtin_bit_cast(bf16x8, H1);                \
        const bf16x8 bl0 = __builtin_bit_cast(bf16x8, L0);                \
        const bf16x8 bl1 = __builtin_bit_cast(bf16x8, L1);                \
        f32x4 acc0 = {0.f, 0.f, 0.f, 0.f};                                \
        f32x4 acc1 = {0.f, 0.f, 0.f, 0.f};                                \
        acc0 = __builtin_amdgcn_mfma_f32_16x16x32_bf16(ah[0], bh0, acc0, 0, 0, 0); \
        acc1 = __builtin_amdgcn_mfma_f32_16x16x32_bf16(ah[1], bh1, acc1, 0, 0, 0); \
        acc0 = __builtin_amdgcn_mfma_f32_16x16x32_bf16(al[0], bh0, acc0, 0, 0, 0); \
        acc1 = __builtin_amdgcn_mfma_f32_16x16x32_bf16(al[1], bh1, acc1, 0, 0, 0); \
        acc0 = __builtin_amdgcn_mfma_f32_16x16x32_bf16(ah[0], bl0, acc0, 0, 0, 0); \
        acc1 = __builtin_amdgcn_mfma_f32_16x16x32_bf16(ah[1], bl1, acc1, 0, 0, 0); \
        const int ki = (CT) * 16 + lc;                                    \
        _Pragma("unroll")                                                 \
        for (int rg = 0; rg < 4; ++rg) {                                  \
            const float s  = fmaf(-2.0f, acc0[rg] + acc1[rg], NV);        \
            const bool  lt = s < b1[rg];                                  \
            const float m2 = fminf(s, b2[rg]);                            \
            b2[rg] = lt ? b1[rg] : m2;                                    \
            b1[rg] = lt ? s      : b1[rg];                                \
            i1[rg] = lt ? ki     : i1[rg];                                \
        }                                                                 \
    }

    {
        int4 Ah0, Ah1, Al0, Al1; float Anv;
        int4 Bh0, Bh1, Bl0, Bl1; float Bnv;
        LOADCT(0, Ah0, Ah1, Al0, Al1, Anv);
        for (int ct = 0; ct < 64; ct += 2) {
            LOADCT(ct + 1, Bh0, Bh1, Bl0, Bl1, Bnv);
            COMPUTECT(ct, Ah0, Ah1, Al0, Al1, Anv);
            const int nct = (ct + 2 < 64) ? (ct + 2) : 0;   // clamped prefetch
            LOADCT(nct, Ah0, Ah1, Al0, Al1, Anv);
            COMPUTECT(ct + 1, Bh0, Bh1, Bl0, Bl1, Bnv);
        }
    }
#undef LOADCT
#undef COMPUTECT

    // Merge top-2 across the 16 lanes sharing rows (lex (score,idx)).
#pragma unroll
    for (int rg = 0; rg < 4; ++rg)
#pragma unroll
        for (int off = 1; off <= 8; off <<= 1) {
            const float ob1 = __shfl_xor(b1[rg], off);
            const float ob2 = __shfl_xor(b2[rg], off);
            const int   oi1 = __shfl_xor(i1[rg], off);
            if (ob1 < b1[rg] || (ob1 == b1[rg] && oi1 < i1[rg])) {
                b2[rg] = fminf(b1[rg], ob2); b1[rg] = ob1; i1[rg] = oi1;
            } else {
                b2[rg] = fminf(ob1, b2[rg]);
            }
        }

    // Near-tie rows: wave-cooperative EXACT fp64 full-K rescan (rare).
#pragma unroll
    for (int rg = 0; rg < 4; ++rg) {
        for (int g = 0; g < 4; ++g) {              // runtime loop, wave-uniform
            const float g1 = __shfl(b1[rg], g << 4);
            const float g2 = __shfl(b2[rg], g << 4);
            if (g2 - g1 < MARGIN) {
                const int grow = wrow0 + g * 4 + rg;
                const float* xp = z_e + (size_t)grow * D_;
                double bs = 1.0e300; int bi = 1 << 30;
                for (int c0 = 0; c0 < K_; c0 += 64) {
                    const int c = c0 + lane;
                    const float* ep = embed + (size_t)c * D_;
                    double dot = 0.0;
#pragma unroll
                    for (int j = 0; j < D_; ++j)
                        dot = fma((double)xp[j], (double)ep[j], dot);
                    const double sc = fma(-2.0, dot, n64g[c]);
                    if (sc < bs) { bs = sc; bi = c; }
                }
#pragma unroll
                for (int off = 32; off > 0; off >>= 1) {   // (s,idx) lex-min
                    const double so = __shfl_xor(bs, off);
                    const int    io = __shfl_xor(bi, off);
                    if (so < bs || (so == bs && io < bi)) { bs = so; bi = io; }
                }
                if (lg == g) i1[rg] = bi;
            }
        }
    }

    // Epilogue: lane owns row lc, k-chunk lg*16..+16.
    float sq = 0.f;
    {
        const int srcl = (lc >> 2) << 4;   // a lane of the group owning row lc
        const int c0v = __shfl(i1[0], srcl);
        const int c1v = __shfl(i1[1], srcl);
        const int c2v = __shfl(i1[2], srcl);
        const int c3v = __shfl(i1[3], srcl);
        const int rsel = lc & 3;
        int bidx = (rsel == 0) ? c0v : (rsel == 1) ? c1v : (rsel == 2) ? c2v : c3v;
        bidx &= (K_ - 1);
        const int row = wrow0 + lc;
        const float4* eg = (const float4*)(embed + (size_t)bidx * D_ + lg * 16);
        float4*       og = (float4*)(out + (size_t)row * D_ + lg * 16);
#pragma unroll
        for (int q = 0; q < 4; ++q) {
            const float4 e = eg[q];
            const int   x0 = q * 4;
            const float d0 = e.x - xs[x0 + 0];
            const float d1 = e.y - xs[x0 + 1];
            const float d2 = e.z - xs[x0 + 2];
            const float d3 = e.w - xs[x0 + 3];
            sq = fmaf(d0, d0, sq); sq = fmaf(d1, d1, sq);
            sq = fmaf(d2, d2, sq); sq = fmaf(d3, d3, sq);
            float4 o;                      // x + (e - x): match reference fp32 rounding
            o.x = xs[x0 + 0] + d0;
            o.y = xs[x0 + 1] + d1;
            o.z = xs[x0 + 2] + d2;
            o.w = xs[x0 + 3] + d3;
            og[q] = o;
        }
        if (lg == 0) out[(size_t)N_ * D_ + row] = (float)bidx;
    }

    // Block loss reduction
    red[tid] = sq;
    __syncthreads();
#pragma unroll
    for (int s = TPB / 2; s > 0; s >>= 1) {
        if (tid < s) red[tid] += red[tid + s];
        __syncthreads();
    }
    if (tid == 0) partials[blockIdx.x] = red[0];
}

// ---------------------------------------------------------------------------
// Kernel C: reduce NBLK partials -> vq_loss = 1.25 * mean(sqdiff), fp32
// ---------------------------------------------------------------------------
__global__ __launch_bounds__(256) void vq_loss_final(const float* __restrict__ partials,
                                                     float* __restrict__ out) {
    __shared__ float red[256];
    const int tid = threadIdx.x;
    float s = 0.f;
#pragma unroll
    for (int i = 0; i < NBLK / 256; ++i) s += partials[tid + i * 256];
    red[tid] = s;
    __syncthreads();
#pragma unroll
    for (int w = 128; w > 0; w >>= 1) {
        if (tid < w) red[tid] += red[tid + w];
        __syncthreads();
    }
    if (tid == 0)
        out[(size_t)N_ * D_ + N_] = 1.25f * red[0] / (float)((size_t)N_ * D_);
}

// ---------------------------------------------------------------------------
extern "C" void kernel_launch(void* const* d_in, const int* in_sizes, int n_in,
                              void* d_out, int out_size, void* d_ws, size_t ws_size,
                              hipStream_t stream) {
    const float* z_e;
    const float* embed;
    if (in_sizes[0] == N_ * D_) {
        z_e   = (const float*)d_in[0];
        embed = (const float*)d_in[1];
    } else {
        z_e   = (const float*)d_in[1];
        embed = (const float*)d_in[0];
    }
    float* out = (float*)d_out;

    double* n64           = (double*)d_ws;                       // 8 KB
    float*  n32           = (float*)(n64 + K_);                  // 4 KB
    float*  partials      = n32 + K_;                            // 4 KB
    unsigned short* ehg   = (unsigned short*)(partials + NBLK);  // 128 KB linear
    unsigned short* elg   = ehg + (size_t)K_ * D_;               // 128 KB linear

    vq_prep<<<(K_ * 4) / 256, 256, 0, stream>>>(embed, n64, n32, ehg, elg);
    vq_main<<<NBLK, TPB, 0, stream>>>(z_e, embed, ehg, elg, n32, n64, out, partials);
    vq_loss_final<<<1, 256, 0, stream>>>(partials, out);
}

// Round 7
// 204.621 us; speedup vs baseline: 1.3557x; 1.3557x over previous
//
#include <hip/hip_runtime.h>
#include <hip/hip_bf16.h>
#include <stdint.h>

// B=16, M=4096, D=64, K=1024. fp32 in / fp32 out.
// Output: [z_q_st (N*D) | indices (N) | loss (1)], fp32.
//
// R18 post-mortem: barrier-free L2-stream was right, the ADDRESSES were
// wrong: lane stride 128B -> each 16B/lane load touched 16 cache lines
// (scatter), TA pipe serialized ~10x; waves parked on vmcnt (VALUBusy 13%,
// MfmaUtil 4.5%) while L2-BW floor is only ~30us.
// R19: permute the staged codebook so the wave reads are COALESCED BY
// CONSTRUCTION: code cl chunk (lg,s) lives at ct*4096 + (lg*16+cl)*32 +
// s*16 (+2048 for lo) => main-loop load address = base + lane*32; each of
// the 4 loads/iter is one contiguous aligned 1KB wave-transaction.
// Everything else identical to R18 (absmax=0): bf16 hi/lo hh+hl+lh screen,
// MARGIN=0.06 >= 2x err bound, kappa k-map on BOTH A/B frags, top-2 merge,
// exact fp64 rescan, epilogue; 2-deep named double-buffer (rule #20);
// VGPR target <=128 (waves/CU halves past 128 per m69).
#define D_     64
#define K_     1024
#define N_     65536
#define TPB    256            // 4 waves
#define RPB    64             // 4 waves x 16 rows
#define NBLK   (N_ / RPB)     // 1024 blocks
#define MARGIN 0.06f          // screen err bound ~1.4e-2; need >= 2x

typedef __bf16 bf16x8 __attribute__((ext_vector_type(8)));
typedef float  f32x4  __attribute__((ext_vector_type(4)));

__device__ __forceinline__ unsigned short bf16_rne(float f) {
    union { float f; uint32_t u; } v; v.f = f;
    const uint32_t u = v.u;
    return (unsigned short)((u + 0x7fffu + ((u >> 16) & 1u)) >> 16);
}
__device__ __forceinline__ float bf16_tof(unsigned short h) {
    union { uint32_t u; float f; } v; v.u = ((uint32_t)h) << 16;
    return v.f;
}

// ---------------------------------------------------------------------------
// Kernel A: exact fp64 norms (+fp32 copy) and PERMUTED bf16 hi/lo codebook.
// Per 16-code group ct (4KB block): hi 2KB then lo 2KB; within each, code cl
// chunk (lg,s) at (lg*16+cl)*32 + s*16. 4 threads/code (q4 = lg).
// ---------------------------------------------------------------------------
__global__ __launch_bounds__(256) void vq_prep(const float* __restrict__ embed,
                                               double* __restrict__ n64,
                                               float* __restrict__ n32,
                                               char* __restrict__ eb) {
    const int gid = blockIdx.x * 256 + threadIdx.x;   // 4096 threads
    const int k   = gid >> 2;
    const int q4  = gid & 3;                          // k-chunk lg of this code
    const float4* e4 = (const float4*)(embed + (size_t)k * D_ + q4 * 16);
    double acc = 0.0;
    uint32_t hw[8], lw[8];
#pragma unroll
    for (int q = 0; q < 4; ++q) {
        const float4 e = e4[q];
        float c[4] = {e.x, e.y, e.z, e.w};
        unsigned short hb[4], lb[4];
#pragma unroll
        for (int j = 0; j < 4; ++j) {
            hb[j] = bf16_rne(c[j]);
            lb[j] = bf16_rne(c[j] - bf16_tof(hb[j]));
            acc = fma((double)c[j], (double)c[j], acc);
        }
        hw[q * 2]     = (uint32_t)hb[0] | ((uint32_t)hb[1] << 16);
        hw[q * 2 + 1] = (uint32_t)hb[2] | ((uint32_t)hb[3] << 16);
        lw[q * 2]     = (uint32_t)lb[0] | ((uint32_t)lb[1] << 16);
        lw[q * 2 + 1] = (uint32_t)lb[2] | ((uint32_t)lb[3] << 16);
    }
    // butterfly over the quad -> all 4 lanes hold the full norm
    acc += __shfl_xor(acc, 1);
    acc += __shfl_xor(acc, 2);
    if (q4 == 0) { n64[k] = acc; n32[k] = (float)acc; }
    const int ct = k >> 4, cl = k & 15;
    char* hp = eb + (size_t)ct * 4096        + (q4 * 16 + cl) * 32;
    char* lp = eb + (size_t)ct * 4096 + 2048 + (q4 * 16 + cl) * 32;
    int4 h0; h0.x = hw[0]; h0.y = hw[1]; h0.z = hw[2]; h0.w = hw[3];
    int4 h1; h1.x = hw[4]; h1.y = hw[5]; h1.z = hw[6]; h1.w = hw[7];
    int4 l0; l0.x = lw[0]; l0.y = lw[1]; l0.z = lw[2]; l0.w = lw[3];
    int4 l1; l1.x = lw[4]; l1.y = lw[5]; l1.z = lw[6]; l1.w = lw[7];
    *(int4*)hp = h0; *(int4*)(hp + 16) = h1;
    *(int4*)lp = l0; *(int4*)(lp + 16) = l1;
}

// ---------------------------------------------------------------------------
// Kernel B: barrier-free MFMA screen streaming B-frags from L2 (coalesced) +
// fused per-row top-2 + exact fp64 rescan + epilogue.
// Wave = 16 rows; lane (lg=l>>4, lc=l&15); A-row = lc, code-in-group = lc.
// ---------------------------------------------------------------------------
__global__ __launch_bounds__(TPB) void vq_main(const float* __restrict__ z_e,
                                               const float* __restrict__ embed,
                                               const char* __restrict__ eb,
                                               const float* __restrict__ n32g,
                                               const double* __restrict__ n64g,
                                               float* __restrict__ out,
                                               float* __restrict__ partials) {
    __shared__ float red[TPB];          // loss reduction only (1 KB)

    const int tid  = threadIdx.x;
    const int lane = tid & 63;
    const int w    = tid >> 6;          // wave id 0..3
    const int lg   = lane >> 4;         // k-chunk / row-group 0..3
    const int lc   = lane & 15;         // A-row in tile / code in group
    const int wrow0 = blockIdx.x * RPB + w * 16;

    // ---- x row: fp32 slice (dims lg*16..+16) + bf16 hi/lo A-fragments ----
    float  xs[16];
    bf16x8 ah[2], al[2];
    {
        const int row = wrow0 + lc;
        const float4* xg = (const float4*)(z_e + (size_t)row * D_ + lg * 16);
#pragma unroll
        for (int q = 0; q < 4; ++q) {
            const float4 x = xg[q];
            xs[q * 4 + 0] = x.x; xs[q * 4 + 1] = x.y;
            xs[q * 4 + 2] = x.z; xs[q * 4 + 3] = x.w;
        }
#pragma unroll
        for (int s = 0; s < 2; ++s) {
#pragma unroll
            for (int i = 0; i < 8; ++i) {
                const float xf = xs[s * 8 + i];
                const unsigned short hb = bf16_rne(xf);
                const unsigned short lb = bf16_rne(xf - bf16_tof(hb));
                union { unsigned short u; __bf16 h; } uh, ul;
                uh.u = hb; ul.u = lb;
                ah[s][i] = uh.h;
                al[s][i] = ul.h;
            }
        }
    }

    float b1[4], b2[4];
    int   i1[4];
#pragma unroll
    for (int rg = 0; rg < 4; ++rg) { b1[rg] = 3.4e38f; b2[rg] = 3.4e38f; i1[rg] = 0; }

    // ---- barrier-free K loop: 64 groups of 16 codes, 2-deep pipeline ----
    // lane's slot: 32B at eb[ct*4096 + lane*32] (hi), +2048 (lo) -> each of
    // the 4 loads below is a contiguous aligned 1KB wave transaction.
    const char* ebl = eb + lane * 32;

#define LOADCT(CT, H0, H1, L0, L1, NV) {                                  \
        const char* p_ = ebl + (CT) * 4096;                               \
        H0 = *(const int4*)(p_);                                          \
        H1 = *(const int4*)(p_ + 16);                                     \
        L0 = *(const int4*)(p_ + 2048);                                   \
        L1 = *(const int4*)(p_ + 2064);                                   \
        NV = n32g[(CT) * 16 + lc];                                        \
    }
#define COMPUTECT(CT, H0, H1, L0, L1, NV) {                               \
        const bf16x8 bh0 = __builtin_bit_cast(bf16x8, H0);                \
        const bf16x8 bh1 = __builtin_bit_cast(bf16x8, H1);                \
        const bf16x8 bl0 = __builtin_bit_cast(bf16x8, L0);                \
        const bf16x8 bl1 = __builtin_bit_cast(bf16x8, L1);                \
        f32x4 acc0 = {0.f, 0.f, 0.f, 0.f};                                \
        f32x4 acc1 = {0.f, 0.f, 0.f, 0.f};                                \
        acc0 = __builtin_amdgcn_mfma_f32_16x16x32_bf16(ah[0], bh0, acc0, 0, 0, 0); \
        acc1 = __builtin_amdgcn_mfma_f32_16x16x32_bf16(ah[1], bh1, acc1, 0, 0, 0); \
        acc0 = __builtin_amdgcn_mfma_f32_16x16x32_bf16(al[0], bh0, acc0, 0, 0, 0); \
        acc1 = __builtin_amdgcn_mfma_f32_16x16x32_bf16(al[1], bh1, acc1, 0, 0, 0); \
        acc0 = __builtin_amdgcn_mfma_f32_16x16x32_bf16(ah[0], bl0, acc0, 0, 0, 0); \
        acc1 = __builtin_amdgcn_mfma_f32_16x16x32_bf16(ah[1], bl1, acc1, 0, 0, 0); \
        const int ki = (CT) * 16 + lc;                                    \
        _Pragma("unroll")                                                 \
        for (int rg = 0; rg < 4; ++rg) {                                  \
            const float s  = fmaf(-2.0f, acc0[rg] + acc1[rg], NV);        \
            const bool  lt = s < b1[rg];                                  \
            const float m2 = fminf(s, b2[rg]);                            \
            b2[rg] = lt ? b1[rg] : m2;                                    \
            b1[rg] = lt ? s      : b1[rg];                                \
            i1[rg] = lt ? ki     : i1[rg];                                \
        }                                                                 \
    }

    {
        int4 Ah0, Ah1, Al0, Al1; float Anv;
        int4 Bh0, Bh1, Bl0, Bl1; float Bnv;
        LOADCT(0, Ah0, Ah1, Al0, Al1, Anv);
        for (int ct = 0; ct < 64; ct += 2) {
            LOADCT(ct + 1, Bh0, Bh1, Bl0, Bl1, Bnv);
            COMPUTECT(ct, Ah0, Ah1, Al0, Al1, Anv);
            const int nct = (ct + 2 < 64) ? (ct + 2) : 0;   // clamped prefetch
            LOADCT(nct, Ah0, Ah1, Al0, Al1, Anv);
            COMPUTECT(ct + 1, Bh0, Bh1, Bl0, Bl1, Bnv);
        }
    }
#undef LOADCT
#undef COMPUTECT

    // Merge top-2 across the 16 lanes sharing rows (lex (score,idx)).
#pragma unroll
    for (int rg = 0; rg < 4; ++rg)
#pragma unroll
        for (int off = 1; off <= 8; off <<= 1) {
            const float ob1 = __shfl_xor(b1[rg], off);
            const float ob2 = __shfl_xor(b2[rg], off);
            const int   oi1 = __shfl_xor(i1[rg], off);
            if (ob1 < b1[rg] || (ob1 == b1[rg] && oi1 < i1[rg])) {
                b2[rg] = fminf(b1[rg], ob2); b1[rg] = ob1; i1[rg] = oi1;
            } else {
                b2[rg] = fminf(ob1, b2[rg]);
            }
        }

    // Near-tie rows: wave-cooperative EXACT fp64 full-K rescan (rare).
#pragma unroll
    for (int rg = 0; rg < 4; ++rg) {
        for (int g = 0; g < 4; ++g) {              // runtime loop, wave-uniform
            const float g1 = __shfl(b1[rg], g << 4);
            const float g2 = __shfl(b2[rg], g << 4);
            if (g2 - g1 < MARGIN) {
                const int grow = wrow0 + g * 4 + rg;
                const float* xp = z_e + (size_t)grow * D_;
                double bs = 1.0e300; int bi = 1 << 30;
                for (int c0 = 0; c0 < K_; c0 += 64) {
                    const int c = c0 + lane;
                    const float* ep = embed + (size_t)c * D_;
                    double dot = 0.0;
#pragma unroll
                    for (int j = 0; j < D_; ++j)
                        dot = fma((double)xp[j], (double)ep[j], dot);
                    const double sc = fma(-2.0, dot, n64g[c]);
                    if (sc < bs) { bs = sc; bi = c; }
                }
#pragma unroll
                for (int off = 32; off > 0; off >>= 1) {   // (s,idx) lex-min
                    const double so = __shfl_xor(bs, off);
                    const int    io = __shfl_xor(bi, off);
                    if (so < bs || (so == bs && io < bi)) { bs = so; bi = io; }
                }
                if (lg == g) i1[rg] = bi;
            }
        }
    }

    // Epilogue: lane owns row lc, k-chunk lg*16..+16.
    float sq = 0.f;
    {
        const int srcl = (lc >> 2) << 4;   // a lane of the group owning row lc
        const int c0v = __shfl(i1[0], srcl);
        const int c1v = __shfl(i1[1], srcl);
        const int c2v = __shfl(i1[2], srcl);
        const int c3v = __shfl(i1[3], srcl);
        const int rsel = lc & 3;
        int bidx = (rsel == 0) ? c0v : (rsel == 1) ? c1v : (rsel == 2) ? c2v : c3v;
        bidx &= (K_ - 1);
        const int row = wrow0 + lc;
        const float4* eg = (const float4*)(embed + (size_t)bidx * D_ + lg * 16);
        float4*       og = (float4*)(out + (size_t)row * D_ + lg * 16);
#pragma unroll
        for (int q = 0; q < 4; ++q) {
            const float4 e = eg[q];
            const int   x0 = q * 4;
            const float d0 = e.x - xs[x0 + 0];
            const float d1 = e.y - xs[x0 + 1];
            const float d2 = e.z - xs[x0 + 2];
            const float d3 = e.w - xs[x0 + 3];
            sq = fmaf(d0, d0, sq); sq = fmaf(d1, d1, sq);
            sq = fmaf(d2, d2, sq); sq = fmaf(d3, d3, sq);
            float4 o;                      // x + (e - x): match reference fp32 rounding
            o.x = xs[x0 + 0] + d0;
            o.y = xs[x0 + 1] + d1;
            o.z = xs[x0 + 2] + d2;
            o.w = xs[x0 + 3] + d3;
            og[q] = o;
        }
        if (lg == 0) out[(size_t)N_ * D_ + row] = (float)bidx;
    }

    // Block loss reduction
    red[tid] = sq;
    __syncthreads();
#pragma unroll
    for (int s = TPB / 2; s > 0; s >>= 1) {
        if (tid < s) red[tid] += red[tid + s];
        __syncthreads();
    }
    if (tid == 0) partials[blockIdx.x] = red[0];
}

// ---------------------------------------------------------------------------
// Kernel C: reduce NBLK partials -> vq_loss = 1.25 * mean(sqdiff), fp32
// ---------------------------------------------------------------------------
__global__ __launch_bounds__(256) void vq_loss_final(const float* __restrict__ partials,
                                                     float* __restrict__ out) {
    __shared__ float red[256];
    const int tid = threadIdx.x;
    float s = 0.f;
#pragma unroll
    for (int i = 0; i < NBLK / 256; ++i) s += partials[tid + i * 256];
    red[tid] = s;
    __syncthreads();
#pragma unroll
    for (int w = 128; w > 0; w >>= 1) {
        if (tid < w) red[tid] += red[tid + w];
        __syncthreads();
    }
    if (tid == 0)
        out[(size_t)N_ * D_ + N_] = 1.25f * red[0] / (float)((size_t)N_ * D_);
}

// ---------------------------------------------------------------------------
extern "C" void kernel_launch(void* const* d_in, const int* in_sizes, int n_in,
                              void* d_out, int out_size, void* d_ws, size_t ws_size,
                              hipStream_t stream) {
    const float* z_e;
    const float* embed;
    if (in_sizes[0] == N_ * D_) {
        z_e   = (const float*)d_in[0];
        embed = (const float*)d_in[1];
    } else {
        z_e   = (const float*)d_in[1];
        embed = (const float*)d_in[0];
    }
    float* out = (float*)d_out;

    double* n64      = (double*)d_ws;                 // 8 KB
    float*  n32      = (float*)(n64 + K_);            // 4 KB
    float*  partials = n32 + K_;                      // 4 KB
    char*   eb       = (char*)(partials + NBLK);      // 256 KB permuted codebook

    vq_prep<<<(K_ * 4) / 256, 256, 0, stream>>>(embed, n64, n32, eb);
    vq_main<<<NBLK, TPB, 0, stream>>>(z_e, embed, eb, n32, n64, out, partials);
    vq_loss_final<<<1, 256, 0, stream>>>(partials, out);
}

// Round 8
// 193.467 us; speedup vs baseline: 1.4339x; 1.0577x over previous
//
#include <hip/hip_runtime.h>
#include <hip/hip_bf16.h>
#include <stdint.h>

// B=16, M=4096, D=64, K=1024. fp32 in / fp32 out.
// Output: [z_q_st (N*D) | indices (N) | loss (1)], fp32.
//
// R19 post-mortem: coalesced L2-stream = 150us, but 360k cyc/SIMD for ~256
// wave-iterations = 1406 cyc/slot vs ~200 cyc of issue -> stall-window
// bound; R15/R17/R19 (LDS or L2 paths) all converge 138-160us => common
// factor is shallow in-flight window + block lockstep, not memory path.
// R20: (1) 1-wave blocks (TPB=64, 4096 blocks) - zero barriers in main,
// no 4-wave lockstep, wave-level loss reduce; (2) batch 2 code-groups per
// pipeline stage (10 loads in flight, 12 MFMA as 4 indep 3-chains);
// (3) keep VGPR<=128: drop xs from loop live range (rematerialize row in
// epilogue from z_e - L3 hit). Screen math/top-2/rescan identical (absmax=0
// lineage): bf16 hi/lo hh+hl+lh, MARGIN=0.06 >= 2x err bound, kappa k-map
// on BOTH A/B frags; C/D row=(l>>4)*4+rg, col=l&15 (m89/m91-verified).
#define D_     64
#define K_     1024
#define N_     65536
#define TPB    64             // 1 wave per block
#define RPB    16             // 16 rows per block
#define NBLK   (N_ / RPB)     // 4096 blocks
#define MARGIN 0.06f          // screen err bound ~1.4e-2; need >= 2x

typedef __bf16 bf16x8 __attribute__((ext_vector_type(8)));
typedef float  f32x4  __attribute__((ext_vector_type(4)));

__device__ __forceinline__ unsigned short bf16_rne(float f) {
    union { float f; uint32_t u; } v; v.f = f;
    const uint32_t u = v.u;
    return (unsigned short)((u + 0x7fffu + ((u >> 16) & 1u)) >> 16);
}
__device__ __forceinline__ float bf16_tof(unsigned short h) {
    union { uint32_t u; float f; } v; v.u = ((uint32_t)h) << 16;
    return v.f;
}

// ---------------------------------------------------------------------------
// Kernel A: exact fp64 norms (+fp32 copy) and PERMUTED bf16 hi/lo codebook.
// Per 16-code group ct (4KB): hi 2KB | lo 2KB; code cl chunk (lg,s) at
// (lg*16+cl)*32 + s*16. 4 threads/code (q4 = lg). 64 blocks x 64 threads.
// ---------------------------------------------------------------------------
__global__ __launch_bounds__(64) void vq_prep(const float* __restrict__ embed,
                                              double* __restrict__ n64,
                                              float* __restrict__ n32,
                                              char* __restrict__ eb) {
    const int gid = blockIdx.x * 64 + threadIdx.x;    // 4096 threads
    const int k   = gid >> 2;
    const int q4  = gid & 3;                          // k-chunk lg of this code
    const float4* e4 = (const float4*)(embed + (size_t)k * D_ + q4 * 16);
    double accA = 0.0, accB = 0.0;                    // 2 indep fp64 chains
    uint32_t hw[8], lw[8];
#pragma unroll
    for (int q = 0; q < 4; ++q) {
        const float4 e = e4[q];
        float c[4] = {e.x, e.y, e.z, e.w};
        unsigned short hb[4], lb[4];
#pragma unroll
        for (int j = 0; j < 4; ++j) {
            hb[j] = bf16_rne(c[j]);
            lb[j] = bf16_rne(c[j] - bf16_tof(hb[j]));
        }
        accA = fma((double)c[0], (double)c[0], accA);
        accB = fma((double)c[1], (double)c[1], accB);
        accA = fma((double)c[2], (double)c[2], accA);
        accB = fma((double)c[3], (double)c[3], accB);
        hw[q * 2]     = (uint32_t)hb[0] | ((uint32_t)hb[1] << 16);
        hw[q * 2 + 1] = (uint32_t)hb[2] | ((uint32_t)hb[3] << 16);
        lw[q * 2]     = (uint32_t)lb[0] | ((uint32_t)lb[1] << 16);
        lw[q * 2 + 1] = (uint32_t)lb[2] | ((uint32_t)lb[3] << 16);
    }
    double acc = accA + accB;
    // butterfly over the quad -> all 4 lanes hold the full norm
    acc += __shfl_xor(acc, 1);
    acc += __shfl_xor(acc, 2);
    if (q4 == 0) { n64[k] = acc; n32[k] = (float)acc; }
    const int ct = k >> 4, cl = k & 15;
    char* hp = eb + (size_t)ct * 4096        + (q4 * 16 + cl) * 32;
    char* lp = eb + (size_t)ct * 4096 + 2048 + (q4 * 16 + cl) * 32;
    int4 h0; h0.x = hw[0]; h0.y = hw[1]; h0.z = hw[2]; h0.w = hw[3];
    int4 h1; h1.x = hw[4]; h1.y = hw[5]; h1.z = hw[6]; h1.w = hw[7];
    int4 l0; l0.x = lw[0]; l0.y = lw[1]; l0.z = lw[2]; l0.w = lw[3];
    int4 l1; l1.x = lw[4]; l1.y = lw[5]; l1.z = lw[6]; l1.w = lw[7];
    *(int4*)hp = h0; *(int4*)(hp + 16) = h1;
    *(int4*)lp = l0; *(int4*)(lp + 16) = l1;
}

// ---------------------------------------------------------------------------
// Kernel B: 1-wave blocks; barrier-free MFMA screen, 2-group pipeline stages
// (10 loads / 12 MFMA per stage), fused top-2 + exact fp64 rescan + epilogue.
// Lane (lg=l>>4, lc=l&15): A-row lc, code-in-group lc, k-chunk lg.
// ---------------------------------------------------------------------------
__global__ __launch_bounds__(TPB) void vq_main(const float* __restrict__ z_e,
                                               const float* __restrict__ embed,
                                               const char* __restrict__ eb,
                                               const float* __restrict__ n32g,
                                               const double* __restrict__ n64g,
                                               float* __restrict__ out,
                                               float* __restrict__ partials) {
    const int lane = threadIdx.x;       // 0..63
    const int lg   = lane >> 4;         // k-chunk / row-group 0..3
    const int lc   = lane & 15;         // A-row in tile / code in group
    const int wrow0 = blockIdx.x * RPB;

    // ---- A-fragments (bf16 hi/lo) from this lane's row slice ----
    bf16x8 ah[2], al[2];
    {
        const float4* xg = (const float4*)(z_e + (size_t)(wrow0 + lc) * D_ + lg * 16);
        float xs[16];
#pragma unroll
        for (int q = 0; q < 4; ++q) {
            const float4 x = xg[q];
            xs[q * 4 + 0] = x.x; xs[q * 4 + 1] = x.y;
            xs[q * 4 + 2] = x.z; xs[q * 4 + 3] = x.w;
        }
#pragma unroll
        for (int s = 0; s < 2; ++s) {
#pragma unroll
            for (int i = 0; i < 8; ++i) {
                const float xf = xs[s * 8 + i];
                const unsigned short hb = bf16_rne(xf);
                const unsigned short lb = bf16_rne(xf - bf16_tof(hb));
                union { unsigned short u; __bf16 h; } uh, ul;
                uh.u = hb; ul.u = lb;
                ah[s][i] = uh.h;
                al[s][i] = ul.h;
            }
        }
    }

    float b1[4], b2[4];
    int   i1[4];
#pragma unroll
    for (int rg = 0; rg < 4; ++rg) { b1[rg] = 3.4e38f; b2[rg] = 3.4e38f; i1[rg] = 0; }

    // ---- barrier-free K loop: 32 pairs of 16-code groups, 2-deep pairs ----
    const char* ebl = eb + lane * 32;   // lane slot: +g*4096 (hi), +2048 (lo)

#define LOADPAIR(P, R) {                                                  \
        const char* p0_ = ebl + (size_t)(P) * 8192;                       \
        R##h00 = *(const int4*)(p0_);                                     \
        R##h01 = *(const int4*)(p0_ + 16);                                \
        R##l00 = *(const int4*)(p0_ + 2048);                              \
        R##l01 = *(const int4*)(p0_ + 2064);                              \
        R##h10 = *(const int4*)(p0_ + 4096);                              \
        R##h11 = *(const int4*)(p0_ + 4112);                              \
        R##l10 = *(const int4*)(p0_ + 6144);                              \
        R##l11 = *(const int4*)(p0_ + 6160);                              \
        R##nv0 = n32g[(P) * 32 + lc];                                     \
        R##nv1 = n32g[(P) * 32 + 16 + lc];                                \
    }
#define COMPGROUP(KI, H0, H1, L0, L1, NV) {                               \
        const bf16x8 bh0 = __builtin_bit_cast(bf16x8, H0);                \
        const bf16x8 bh1 = __builtin_bit_cast(bf16x8, H1);                \
        const bf16x8 bl0 = __builtin_bit_cast(bf16x8, L0);                \
        const bf16x8 bl1 = __builtin_bit_cast(bf16x8, L1);                \
        f32x4 acc0 = {0.f, 0.f, 0.f, 0.f};                                \
        f32x4 acc1 = {0.f, 0.f, 0.f, 0.f};                                \
        acc0 = __builtin_amdgcn_mfma_f32_16x16x32_bf16(ah[0], bh0, acc0, 0, 0, 0); \
        acc1 = __builtin_amdgcn_mfma_f32_16x16x32_bf16(ah[1], bh1, acc1, 0, 0, 0); \
        acc0 = __builtin_amdgcn_mfma_f32_16x16x32_bf16(al[0], bh0, acc0, 0, 0, 0); \
        acc1 = __builtin_amdgcn_mfma_f32_16x16x32_bf16(al[1], bh1, acc1, 0, 0, 0); \
        acc0 = __builtin_amdgcn_mfma_f32_16x16x32_bf16(ah[0], bl0, acc0, 0, 0, 0); \
        acc1 = __builtin_amdgcn_mfma_f32_16x16x32_bf16(ah[1], bl1, acc1, 0, 0, 0); \
        const int ki_ = (KI) + lc;                                        \
        _Pragma("unroll")                                                 \
        for (int rg = 0; rg < 4; ++rg) {                                  \
            const float s  = fmaf(-2.0f, acc0[rg] + acc1[rg], NV);        \
            const bool  lt = s < b1[rg];                                  \
            const float m2 = fminf(s, b2[rg]);                            \
            b2[rg] = lt ? b1[rg] : m2;                                    \
            b1[rg] = lt ? s      : b1[rg];                                \
            i1[rg] = lt ? ki_    : i1[rg];                                \
        }                                                                 \
    }
#define COMPPAIR(P, R) {                                                  \
        COMPGROUP((P) * 32,      R##h00, R##h01, R##l00, R##l01, R##nv0); \
        COMPGROUP((P) * 32 + 16, R##h10, R##h11, R##l10, R##l11, R##nv1); \
    }

    {
        int4 Ah00, Ah01, Al00, Al01, Ah10, Ah11, Al10, Al11; float Anv0, Anv1;
        int4 Bh00, Bh01, Bl00, Bl01, Bh10, Bh11, Bl10, Bl11; float Bnv0, Bnv1;
        LOADPAIR(0, A);
        for (int p = 0; p < 32; p += 2) {
            LOADPAIR(p + 1, B);
            COMPPAIR(p, A);
            const int np = (p + 2 < 32) ? (p + 2) : 0;   // clamped prefetch
            LOADPAIR(np, A);
            COMPPAIR(p + 1, B);
        }
    }
#undef LOADPAIR
#undef COMPGROUP
#undef COMPPAIR

    // Merge top-2 across the 16 lanes sharing rows (lex (score,idx)).
#pragma unroll
    for (int rg = 0; rg < 4; ++rg)
#pragma unroll
        for (int off = 1; off <= 8; off <<= 1) {
            const float ob1 = __shfl_xor(b1[rg], off);
            const float ob2 = __shfl_xor(b2[rg], off);
            const int   oi1 = __shfl_xor(i1[rg], off);
            if (ob1 < b1[rg] || (ob1 == b1[rg] && oi1 < i1[rg])) {
                b2[rg] = fminf(b1[rg], ob2); b1[rg] = ob1; i1[rg] = oi1;
            } else {
                b2[rg] = fminf(ob1, b2[rg]);
            }
        }

    // Near-tie rows: wave-cooperative EXACT fp64 full-K rescan (rare).
#pragma unroll
    for (int rg = 0; rg < 4; ++rg) {
        for (int g = 0; g < 4; ++g) {              // runtime loop, wave-uniform
            const float g1 = __shfl(b1[rg], g << 4);
            const float g2 = __shfl(b2[rg], g << 4);
            if (g2 - g1 < MARGIN) {
                const int grow = wrow0 + g * 4 + rg;
                const float* xp = z_e + (size_t)grow * D_;
                double bs = 1.0e300; int bi = 1 << 30;
                for (int c0 = 0; c0 < K_; c0 += 64) {
                    const int c = c0 + lane;
                    const float* ep = embed + (size_t)c * D_;
                    double dot = 0.0;
#pragma unroll
                    for (int j = 0; j < D_; ++j)
                        dot = fma((double)xp[j], (double)ep[j], dot);
                    const double sc = fma(-2.0, dot, n64g[c]);
                    if (sc < bs) { bs = sc; bi = c; }
                }
#pragma unroll
                for (int off = 32; off > 0; off >>= 1) {   // (s,idx) lex-min
                    const double so = __shfl_xor(bs, off);
                    const int    io = __shfl_xor(bi, off);
                    if (so < bs || (so == bs && io < bi)) { bs = so; bi = io; }
                }
                if (lg == g) i1[rg] = bi;
            }
        }
    }

    // Epilogue: lane owns row lc, k-chunk lg*16..+16; x rematerialized.
    float sq = 0.f;
    {
        const int srcl = (lc >> 2) << 4;   // a lane of the group owning row lc
        const int c0v = __shfl(i1[0], srcl);
        const int c1v = __shfl(i1[1], srcl);
        const int c2v = __shfl(i1[2], srcl);
        const int c3v = __shfl(i1[3], srcl);
        const int rsel = lc & 3;
        int bidx = (rsel == 0) ? c0v : (rsel == 1) ? c1v : (rsel == 2) ? c2v : c3v;
        bidx &= (K_ - 1);
        const int row = wrow0 + lc;
        const float4* eg = (const float4*)(embed + (size_t)bidx * D_ + lg * 16);
        const float4* xg = (const float4*)(z_e + (size_t)row * D_ + lg * 16);
        float4*       og = (float4*)(out + (size_t)row * D_ + lg * 16);
#pragma unroll
        for (int q = 0; q < 4; ++q) {
            const float4 e = eg[q];
            const float4 x = xg[q];
            const float d0 = e.x - x.x;
            const float d1 = e.y - x.y;
            const float d2 = e.z - x.z;
            const float d3 = e.w - x.w;
            sq = fmaf(d0, d0, sq); sq = fmaf(d1, d1, sq);
            sq = fmaf(d2, d2, sq); sq = fmaf(d3, d3, sq);
            float4 o;                      // x + (e - x): match reference fp32 rounding
            o.x = x.x + d0;
            o.y = x.y + d1;
            o.z = x.z + d2;
            o.w = x.w + d3;
            og[q] = o;
        }
        if (lg == 0) out[(size_t)N_ * D_ + row] = (float)bidx;
    }

    // Wave-level loss reduction (no LDS, no barriers)
#pragma unroll
    for (int off = 32; off > 0; off >>= 1) sq += __shfl_xor(sq, off);
    if (lane == 0) partials[blockIdx.x] = sq;
}

// ---------------------------------------------------------------------------
// Kernel C: reduce NBLK partials -> vq_loss = 1.25 * mean(sqdiff), fp32
// ---------------------------------------------------------------------------
__global__ __launch_bounds__(256) void vq_loss_final(const float* __restrict__ partials,
                                                     float* __restrict__ out) {
    __shared__ float red[256];
    const int tid = threadIdx.x;
    float s = 0.f;
#pragma unroll
    for (int i = 0; i < NBLK / 256; ++i) s += partials[tid + i * 256];
    red[tid] = s;
    __syncthreads();
#pragma unroll
    for (int w = 128; w > 0; w >>= 1) {
        if (tid < w) red[tid] += red[tid + w];
        __syncthreads();
    }
    if (tid == 0)
        out[(size_t)N_ * D_ + N_] = 1.25f * red[0] / (float)((size_t)N_ * D_);
}

// ---------------------------------------------------------------------------
extern "C" void kernel_launch(void* const* d_in, const int* in_sizes, int n_in,
                              void* d_out, int out_size, void* d_ws, size_t ws_size,
                              hipStream_t stream) {
    const float* z_e;
    const float* embed;
    if (in_sizes[0] == N_ * D_) {
        z_e   = (const float*)d_in[0];
        embed = (const float*)d_in[1];
    } else {
        z_e   = (const float*)d_in[1];
        embed = (const float*)d_in[0];
    }
    float* out = (float*)d_out;

    double* n64      = (double*)d_ws;                 // 8 KB
    float*  n32      = (float*)(n64 + K_);            // 4 KB
    float*  partials = n32 + K_;                      // 16 KB
    char*   eb       = (char*)(partials + NBLK);      // 256 KB permuted codebook

    vq_prep<<<K_ / 16, 64, 0, stream>>>(embed, n64, n32, eb);
    vq_main<<<NBLK, TPB, 0, stream>>>(z_e, embed, eb, n32, n64, out, partials);
    vq_loss_final<<<1, 256, 0, stream>>>(partials, out);
}